// Round 1
// baseline (5997.617 us; speedup 1.0000x reference)
//
#include <hip/hip_runtime.h>
#include <hip/hip_bf16.h>
#include <math.h>

#define B_ 16
#define S_ 512
#define E_ 300
#define H_ 512
#define V_ 10000
#define BS_ (B_ * S_)  // 8192

// ---------------------------------------------------------------------------
// K1: xw[bs,h] = sum_e x[bs,e] * W_ih[h,e] + b_ih[h] + b_hh[h]
// 16x16 output tile per block, full K (E=300) staged in LDS, pad 301 (odd
// stride => 16 distinct banks for the Ws[j][e] reads; As[i][e] is broadcast).
// ---------------------------------------------------------------------------
__global__ __launch_bounds__(256) void k1_xw(const float* __restrict__ x,
                                             const float* __restrict__ W_ih,
                                             const float* __restrict__ b_ih,
                                             const float* __restrict__ b_hh,
                                             float* __restrict__ xw) {
  __shared__ float As[16][301];
  __shared__ float Ws[16][301];
  const int row0 = blockIdx.x * 16;  // bs
  const int col0 = blockIdx.y * 16;  // h
  const int tid = threadIdx.x;
  for (int idx = tid; idx < 16 * E_; idx += 256) {
    int r = idx / E_, c = idx - r * E_;
    As[r][c] = x[(size_t)(row0 + r) * E_ + c];
    Ws[r][c] = W_ih[(size_t)(col0 + r) * E_ + c];
  }
  __syncthreads();
  const int i = tid >> 4, j = tid & 15;
  float acc = 0.f;
#pragma unroll 4
  for (int e = 0; e < E_; ++e) acc += As[i][e] * Ws[j][e];
  const int h = col0 + j;
  xw[(size_t)(row0 + i) * H_ + h] = acc + b_ih[h] + b_hh[h];
}

// ---------------------------------------------------------------------------
// K2a: WT[i][j] = W_hh[j][i]  (so the scan reads W columns coalesced)
// ---------------------------------------------------------------------------
__global__ __launch_bounds__(256) void k2_transpose(const float* __restrict__ W,
                                                    float* __restrict__ WT) {
  const int idx = blockIdx.x * 256 + threadIdx.x;  // = i*H + j
  const int i = idx >> 9, j = idx & (H_ - 1);
  WT[idx] = W[j * H_ + i];
}

// ---------------------------------------------------------------------------
// K2b: the sequential scan. One block per batch row (fully independent).
// 1024 threads: thread (half, j) accumulates i in [half*256, half*256+256).
// h lives in LDS; W streams from L2 (1 MB / step). 3 barriers per step.
// ---------------------------------------------------------------------------
__global__ __launch_bounds__(1024) void k2_scan(const float* __restrict__ xw,
                                                const float* __restrict__ WT,
                                                float* __restrict__ hs) {
  const int b = blockIdx.x;
  const int tid = threadIdx.x;
  const int j = tid & (H_ - 1);
  const int half = tid >> 9;  // wave-uniform
  __shared__ float hbuf[H_];
  __shared__ float part[H_];
  if (tid < H_) hbuf[tid] = 0.f;
  __syncthreads();
  const int i0 = half * 256;
  for (int t = 0; t < S_; ++t) {
    float acc = half ? 0.f : xw[((size_t)b * S_ + t) * H_ + j];
#pragma unroll 8
    for (int i = 0; i < 256; ++i) {
      acc += WT[(size_t)(i0 + i) * H_ + j] * hbuf[i0 + i];
    }
    __syncthreads();  // all hbuf reads for step t done
    if (half) part[j] = acc;
    __syncthreads();  // partials visible
    if (!half) {
      const float hn = tanhf(acc + part[j]);
      hbuf[j] = hn;
      hs[((size_t)b * S_ + t) * H_ + j] = hn;
    }
    __syncthreads();  // hbuf updated before next step's reads
  }
}

// ---------------------------------------------------------------------------
// K3: logits[bs,v] = sum_h hs[bs,h] * W_fc[v,h] + b_fc[v]   (into d_out)
// 128x128 tile, 8x8 micro-tile per thread, K staged 8 at a time, k-major LDS
// so fragments are contiguous float4 reads.
// ---------------------------------------------------------------------------
__global__ __launch_bounds__(256) void k3_logits(const float* __restrict__ hs,
                                                 const float* __restrict__ W_fc,
                                                 const float* __restrict__ b_fc,
                                                 float* __restrict__ out) {
  __shared__ float As[8][128];
  __shared__ float Bs[8][128];
  const int m0 = blockIdx.x * 128;
  const int n0 = blockIdx.y * 128;
  const int tid = threadIdx.x;
  const int tx = tid & 15, ty = tid >> 4;
  float acc[8][8];
#pragma unroll
  for (int i = 0; i < 8; ++i)
#pragma unroll
    for (int jj = 0; jj < 8; ++jj) acc[i][jj] = 0.f;

  const int rr = tid >> 1;         // 0..127 (tile row)
  const int kq = (tid & 1) * 4;    // 0 or 4 (k sub-chunk)
  const bool bok = (n0 + rr) < V_;

  for (int k0 = 0; k0 < H_; k0 += 8) {
    const float4 av =
        *(const float4*)&hs[(size_t)(m0 + rr) * H_ + k0 + kq];
    float4 bv = make_float4(0.f, 0.f, 0.f, 0.f);
    if (bok) bv = *(const float4*)&W_fc[(size_t)(n0 + rr) * H_ + k0 + kq];
    __syncthreads();  // previous iter's LDS reads done
    As[kq + 0][rr] = av.x; As[kq + 1][rr] = av.y;
    As[kq + 2][rr] = av.z; As[kq + 3][rr] = av.w;
    Bs[kq + 0][rr] = bv.x; Bs[kq + 1][rr] = bv.y;
    Bs[kq + 2][rr] = bv.z; Bs[kq + 3][rr] = bv.w;
    __syncthreads();
#pragma unroll
    for (int kk = 0; kk < 8; ++kk) {
      const float4 a0 = *(const float4*)&As[kk][ty * 8];
      const float4 a1 = *(const float4*)&As[kk][ty * 8 + 4];
      const float4 b0 = *(const float4*)&Bs[kk][tx * 8];
      const float4 b1 = *(const float4*)&Bs[kk][tx * 8 + 4];
      const float a[8] = {a0.x, a0.y, a0.z, a0.w, a1.x, a1.y, a1.z, a1.w};
      const float bb[8] = {b0.x, b0.y, b0.z, b0.w, b1.x, b1.y, b1.z, b1.w};
#pragma unroll
      for (int i = 0; i < 8; ++i)
#pragma unroll
        for (int jj = 0; jj < 8; ++jj) acc[i][jj] += a[i] * bb[jj];
    }
  }
#pragma unroll
  for (int jj = 0; jj < 8; ++jj) {
    const int v = n0 + tx * 8 + jj;
    if (v < V_) {
      const float bias = b_fc[v];
#pragma unroll
      for (int i = 0; i < 8; ++i)
        out[(size_t)(m0 + ty * 8 + i) * V_ + v] = acc[i][jj] + bias;
    }
  }
}

// ---------------------------------------------------------------------------
// K4a: per-(b,v) online max + sum over the S axis (stride-V column reads,
// coalesced across lanes). Stores (m, 1/sum).
// ---------------------------------------------------------------------------
__global__ __launch_bounds__(256) void k4_stats(const float* __restrict__ logits,
                                                float* __restrict__ stats) {
  const int g = blockIdx.x * 256 + threadIdx.x;  // b*V + v, exact grid
  const int b = g / V_;
  const int v = g - b * V_;
  const float* p = logits + (size_t)b * S_ * V_ + v;
  float m = -3.4e38f, sum = 0.f;
  for (int s = 0; s < S_; ++s) {
    const float xv = p[(size_t)s * V_];
    if (xv > m) {
      sum = sum * __expf(m - xv) + 1.f;
      m = xv;
    } else {
      sum += __expf(xv - m);
    }
  }
  stats[2 * g] = m;
  stats[2 * g + 1] = 1.f / sum;
}

// ---------------------------------------------------------------------------
// K4b: in-place normalize: out = exp(l - m) * inv_sum
// ---------------------------------------------------------------------------
__global__ __launch_bounds__(256) void k4_norm(float* __restrict__ logits,
                                               const float* __restrict__ stats) {
  const size_t idx = (size_t)blockIdx.x * 256 + threadIdx.x;
  const int v = (int)(idx % V_);
  const int b = (int)(idx / ((size_t)S_ * V_));
  const int g = b * V_ + v;
  const float m = stats[2 * g];
  const float inv = stats[2 * g + 1];
  logits[idx] = __expf(logits[idx] - m) * inv;
}

extern "C" void kernel_launch(void* const* d_in, const int* in_sizes, int n_in,
                              void* d_out, int out_size, void* d_ws,
                              size_t ws_size, hipStream_t stream) {
  const float* x    = (const float*)d_in[0];
  const float* W_ih = (const float*)d_in[1];
  const float* W_hh = (const float*)d_in[2];
  const float* b_ih = (const float*)d_in[3];
  const float* b_hh = (const float*)d_in[4];
  const float* W_fc = (const float*)d_in[5];
  const float* b_fc = (const float*)d_in[6];
  float* out = (float*)d_out;

  // workspace layout (floats): xw | WT | hs | stats  = 35.9 MB total
  float* ws = (float*)d_ws;
  float* xw = ws;                              // 8192*512
  float* WT = xw + (size_t)BS_ * H_;           // 512*512
  float* hs = WT + (size_t)H_ * H_;            // 8192*512
  float* stats = hs + (size_t)BS_ * H_;        // 2*16*10000

  k1_xw<<<dim3(BS_ / 16, H_ / 16), 256, 0, stream>>>(x, W_ih, b_ih, b_hh, xw);
  k2_transpose<<<(H_ * H_) / 256, 256, 0, stream>>>(W_hh, WT);
  k2_scan<<<B_, 1024, 0, stream>>>(xw, WT, hs);
  k3_logits<<<dim3(BS_ / 128, (V_ + 127) / 128), 256, 0, stream>>>(hs, W_fc,
                                                                   b_fc, out);
  k4_stats<<<(B_ * V_) / 256, 256, 0, stream>>>(out, stats);
  k4_norm<<<(int)((size_t)BS_ * V_ / 256), 256, 0, stream>>>(out, stats);
}